// Round 8
// baseline (219.727 us; speedup 1.0000x reference)
//
#include <hip/hip_runtime.h>
#include <hip/hip_fp16.h>

#define HH 384
#define WW 384
#define HWSZ (HH*WW)   // 147456
#define NB 4

typedef _Float16 f16x8 __attribute__((ext_vector_type(8)));
typedef _Float16 f16x4 __attribute__((ext_vector_type(4)));
typedef _Float16 f16x2 __attribute__((ext_vector_type(2)));
typedef float    f32x4 __attribute__((ext_vector_type(4)));

// ---- ws layout (bytes) ----
// h2 fp16 NHWC [4][384][384][64]: 75,497,472 B @ 0
#define W1A_B 75497472u               // [2 kstep][4 ct][64 lane][8] f16 A-frags, 8192 B
#define W2F_B (W1A_B + 9216u)         // [2][9][4][64][8] f16, 73728 B  (B-frag order)
#define W3F_B (W2F_B + 73728u)        // [2][9][6][64][8] f16, 110592 B (B-frag order, TAP-PERMUTED, co pad 96)
// total 75,691,008 B ~= 72.2 MiB (proven safe)

// w3 output-channel (tap) PERMUTATION: slot p (0..95) -> original tap oc.
// Groups of 4 slots (g = p>>2, i = p&3) map to spatially-regular runs so the
// bokeh gather reads rgbl[base + i*const] (mergeable into ds_read2_b32):
//   g<18 : horizontal run: oc = (g>>1)*9 + (g&1)*4 + i   (ty=g>>1, tx=(g&1)*4+i)
//   g==18: vertical  run: oc = i*9 + 8                   (ty=i,    tx=8)
//   g==19: vertical  run: oc = 44 + 9*i                  (ty=4+i,  tx=8)
//   g==20: single tap 80 (i==0 only)                     (ty=8,    tx=8)
//   else : zero padding
__device__ __forceinline__ int perm_oc(int g, int i, bool& valid) {
  valid = true;
  if (g < 18) return (g >> 1) * 9 + (g & 1) * 4 + i;
  if (g == 18) return i * 9 + 8;
  if (g == 19) return 44 + 9 * i;
  if (g == 20) { valid = (i == 0); return 80; }
  valid = false; return 0;
}

// ---- prep: w1 packed as MFMA A-frags (K = tap*4+ci, 36 -> 2 k-steps of 32),
// w2/w3 packed into MFMA B-fragment order; w3 rows tap-permuted ---- (unchanged)
__global__ __launch_bounds__(256) void prep(const float* __restrict__ w1,
    const float* __restrict__ w2, const float* __restrict__ w3, char* __restrict__ ws) {
  int i = blockIdx.x * 256 + threadIdx.x;
  _Float16* w1a = (_Float16*)(ws + W1A_B);
  _Float16* w2f = (_Float16*)(ws + W2F_B);
  _Float16* w3f = (_Float16*)(ws + W3F_B);
  if (i < 4096) {  // w1a linear: kstep*2048 + ct*512 + l*8 + j
    int kstep = i >> 11, r = i & 2047;
    int ct = r >> 9, l = (r >> 3) & 63, j = i & 7;
    int k = kstep * 32 + (l >> 4) * 8 + j;
    int tap = k >> 2, ci = k & 3;
    int co = ct * 16 + (l & 15);
    w1a[i] = (tap < 9) ? (_Float16)w1[co * 36 + ci * 9 + tap] : (_Float16)0.f;
    return;
  }
  int o = i - 4096;
  if (o < 36864) {  // w2f: [cc][tap][cj][lane][j] strides 18432/2048/512/8/1
    int cc = o / 18432, rem = o % 18432;
    int tap = rem >> 11, r2 = rem & 2047;
    int cj = r2 >> 9, l = (r2 >> 3) & 63, j = r2 & 7;
    int co = cj * 16 + (l & 15);
    int ci = cc * 32 + (l >> 4) * 8 + j;
    w2f[o] = (_Float16)w2[co * 576 + ci * 9 + tap];
    return;
  }
  o -= 36864;
  if (o < 55296) {  // w3f: [cc][tap][cj][lane][j] strides 27648/3072/512/8/1
    int cc = o / 27648, rem = o % 27648;
    int tap = rem / 3072, r2 = rem % 3072;
    int cj = r2 >> 9, l = (r2 >> 3) & 63, j = r2 & 7;
    int p = cj * 16 + (l & 15);          // permuted slot
    int ci = cc * 32 + (l >> 4) * 8 + j;
    bool valid;
    int oc = perm_oc(p >> 2, p & 3, valid);
    w3f[o] = valid ? (_Float16)w3[oc * 576 + ci * 9 + tap] : (_Float16)0.f;
  }
}

// ---- stage 1: conv1 (MFMA) + conv2 (MFMA) -> h2 fp16 NHWC ----
// ROUND-7 LESSON (reverted): T14 reg-prefetch of w2l cost ~7 µs (VGPR/scheduling,
// no exposed latency to hide). THIS ROUND: w2l is DELETED — conv2 reads weight
// frags straight from global (w2f is 73.7 KB, L2/L1-resident; 1 KB coalesced
// wave-loads on the idle VMEM pipe). Removes 576 ds_read_b128/block (the
// 4x-wave-redundant bf half of conv2's LDS traffic), all staging chains, and 4
// barriers/cc. conv12 is LDS-capacity-capped at 4 blocks/CU (36.9 KB smem), so
// VGPR is free to 128 (m69); peak ~120 keeps 4 waves/SIMD. acc fully unrolled
// (R6); no VGPR min-waves cap (R8).
__global__ __launch_bounds__(256) void conv12(
    const float* __restrict__ rgb, const float* __restrict__ depth,
    const float* __restrict__ b1, const float* __restrict__ b2,
    const char* __restrict__ wsro, unsigned short* __restrict__ h2) {
  __shared__ __align__(16) char smem[36864];
  f16x2*    xwh = (f16x2*)smem;                 // 3200 B  [2 cip][20][20] origin (-2,-2)
  _Float16* h1T = (_Float16*)(smem + 3200);     // 20736 B [18*18][32] swizzled
  _Float16* tr  = (_Float16*)smem;              // epilogue alias: [16][16][72] = 36864 B
  const int t = threadIdx.x;
  const int x0 = blockIdx.x * 16, y0 = blockIdx.y * 16, b = blockIdx.z;
  const f16x8* w1af = (const f16x8*)(wsro + W1A_B);   // [kstep][ct][lane]
  const f16x8* w2g  = (const f16x8*)(wsro + W2F_B);   // [(cc*9+tap)*4+cj][lane]
  const int lane = t & 63, q = lane >> 4, n = lane & 15, w = t >> 6;

  // stage input tile as ci-pairs: pair0=(r,g), pair1=(b,depth)
  for (int idx = t; idx < 800; idx += 256) {
    int p = idx / 400, r2 = idx % 400, iy = r2 / 20, ix = r2 % 20;
    int gy = y0 + iy - 2, gx = x0 + ix - 2;
    f16x2 v = {(_Float16)0.f, (_Float16)0.f};
    if ((unsigned)gy < (unsigned)HH && (unsigned)gx < (unsigned)WW) {
      size_t off = (size_t)gy * WW + gx;
      int c0 = p * 2;
      float f0 = rgb[(size_t)(b * 3 + c0) * HWSZ + off];             // c0 = 0 or 2
      float f1 = (c0 + 1 < 3) ? rgb[(size_t)(b * 3 + c0 + 1) * HWSZ + off]
                              : depth[(size_t)b * HWSZ + off];
      v[0] = (_Float16)f0; v[1] = (_Float16)f1;
    }
    xwh[idx] = v;
  }

  f32x4 acc[4][4];
  #pragma unroll
  for (int cj = 0; cj < 4; ++cj) {
    float bv = b2[cj * 16 + n];
    #pragma unroll
    for (int ri = 0; ri < 4; ++ri) acc[ri][cj] = (f32x4){bv, bv, bv, bv};
  }
  __syncthreads();

  for (int cc = 0; cc < 2; ++cc) {
    // per-cc w1 A-frags + bias (STATIC register indexing; cc only in the address)
    f16x8 wa[2][2];
    #pragma unroll
    for (int ks = 0; ks < 2; ++ks)
      #pragma unroll
      for (int c2 = 0; c2 < 2; ++c2)
        wa[ks][c2] = w1af[(ks * 4 + cc * 2 + c2) * 64 + lane];
    float4 bia[2];
    #pragma unroll
    for (int c2 = 0; c2 < 2; ++c2)
      bia[c2] = *(const float4*)&b1[(cc * 2 + c2) * 16 + q * 4];

    // conv1 MFMA: 21 m-tiles of 16 px over the 18x18 halo, waves strided by 4.
    #pragma unroll 1
    for (int tile = w; tile < 21; tile += 4) {
      int px = tile * 16 + n;
      int pxc = px < 323 ? px : 323;           // clamp keeps reads in-bounds/real
      int row = pxc / 18, col = pxc - row * 18;
      bool okp = ((unsigned)(y0 + row - 1) < (unsigned)HH) &&
                 ((unsigned)(x0 + col - 1) < (unsigned)WW);
      // B-frag k-step0: taps q*2, q*2+1; halfs = {ci0..3}@tap0, {ci0..3}@tap1
      int t0 = q * 2, t1 = t0 + 1;
      int ky0 = t0 / 3, kx0 = t0 - ky0 * 3;
      int ky1 = t1 / 3, kx1 = t1 - ky1 * 3;
      f16x2 p00 = xwh[(row + ky0) * 20 + col + kx0];
      f16x2 p01 = xwh[400 + (row + ky0) * 20 + col + kx0];
      f16x2 p10 = xwh[(row + ky1) * 20 + col + kx1];
      f16x2 p11 = xwh[400 + (row + ky1) * 20 + col + kx1];
      f16x8 bf0 = {p00[0], p00[1], p01[0], p01[1], p10[0], p10[1], p11[0], p11[1]};
      // B-frag k-step1: only k=32..35 valid (tap 8, q==0); rest MUST be 0 (A is
      // zero there, and 0*NaN would poison the dot).
      f16x8 bf1 = {};
      if (q == 0) {
        f16x2 p80 = xwh[(row + 2) * 20 + col + 2];
        f16x2 p81 = xwh[400 + (row + 2) * 20 + col + 2];
        bf1[0] = p80[0]; bf1[1] = p80[1]; bf1[2] = p81[0]; bf1[3] = p81[1];
      }
      #pragma unroll
      for (int c2 = 0; c2 < 2; ++c2) {
        f32x4 a = (f32x4){bia[c2].x, bia[c2].y, bia[c2].z, bia[c2].w};
        a = __builtin_amdgcn_mfma_f32_16x16x32_f16(wa[0][c2], bf0, a, 0, 0, 0);
        a = __builtin_amdgcn_mfma_f32_16x16x32_f16(wa[1][c2], bf1, a, 0, 0, 0);
        if (px < 324) {
          f16x4 hv;
          #pragma unroll
          for (int i = 0; i < 4; ++i)
            hv[i] = okp ? (_Float16)fmaxf(a[i], 0.f) : (_Float16)0.f;
          int g = c2 * 2 + (q >> 1);           // co_in_cc = c2*16+q*4+i; g = /8
          *(f16x4*)&h1T[pxc * 32 + ((g ^ (col & 3)) * 8 + (q & 1) * 4)] = hv;
        }
      }
    }
    __syncthreads();

    // conv2 MFMA: 9 taps (tg=ty, tt=tx); bf frags DIRECT FROM GLOBAL (L2/L1),
    // af from h1T. No internal barriers — h1T is read-only until the cc ends.
    #pragma unroll 1
    for (int tg = 0; tg < 3; ++tg) {
      #pragma unroll
      for (int tt = 0; tt < 3; ++tt) {
        f16x8 bfr[4];
        #pragma unroll
        for (int cj = 0; cj < 4; ++cj)
          bfr[cj] = w2g[(size_t)(((cc * 9 + tg * 3 + tt) * 4 + cj) * 64 + lane)];
        f16x8 af[4];
        #pragma unroll
        for (int ri = 0; ri < 4; ++ri) {
          int row = w * 4 + ri + tg;           // 0..17
          int col = n + tt;                    // A-frag m = lane&15 = x
          af[ri] = *(const f16x8*)&h1T[(row * 18 + col) * 32 + ((q ^ (col & 3)) * 8)];
        }
        #pragma unroll
        for (int cj = 0; cj < 4; ++cj)
          #pragma unroll
          for (int ri = 0; ri < 4; ++ri)
            acc[ri][cj] = __builtin_amdgcn_mfma_f32_16x16x32_f16(af[ri], bfr[cj], acc[ri][cj], 0, 0, 0);
      }
    }
    __syncthreads();                            // protect h1T before next cc / tr alias
  }

  // epilogue: ReLU + fp16, transpose via LDS (tr aliases all of smem), NHWC store.
  // D layout: x = q*4+i, co = cj*16+n, y = w*4+ri.
  #pragma unroll
  for (int ri = 0; ri < 4; ++ri) {
    int py = w * 4 + ri;
    #pragma unroll
    for (int cj = 0; cj < 4; ++cj)
      #pragma unroll
      for (int i = 0; i < 4; ++i)
        tr[(py * 16 + q * 4 + i) * 72 + cj * 16 + n] = (_Float16)fmaxf(acc[ri][cj][i], 0.f);
  }
  __syncthreads();
  #pragma unroll
  for (int k = 0; k < 8; ++k) {
    int idx = t + k * 256;                     // [0,2048): y | x | c8
    int y = idx >> 7, x = (idx >> 3) & 15, c8 = (idx & 7) * 8;
    f16x8 v = *(const f16x8*)&tr[(y * 16 + x) * 72 + c8];
    *(f16x8*)&h2[(((size_t)b * HH + y0 + y) * WW + x0 + x) * 64 + c8] = v;
  }
}

// ---- stage 2: conv3 (MFMA) + softmax + bokeh ---- (FROZEN — control, round-6 form)
// At its structural LDS floor (~89% LDS-pipe busy): tap-split restructures are
// a wash, wider tiles hit the R4 register cliff, fp8 operands break absmax.
__global__ __launch_bounds__(512) void conv3bokeh(
    const unsigned short* __restrict__ h2, const float* __restrict__ rgb,
    const float* __restrict__ b3, const char* __restrict__ wsro,
    float* __restrict__ out) {
  __shared__ __align__(16) char smem[40224];
  _Float16* h2T  = (_Float16*)smem;             // 20736 B [18*18][32] swizzled
  _Float16* w3l  = (_Float16*)(smem + 20736);   // 12288 B = 2 x [mt 6][lane 64][8] ping-pong
  float*    rgbl = (float*)(smem + 33024);      // 7200 B [24 row][3 ch][25 col], origin (-4,-4)
  const int t = threadIdx.x;
  const int x0 = blockIdx.x * 16, y0 = blockIdx.y * 16, b = blockIdx.z;
  const _Float16* w3f = (const _Float16*)(wsro + W3F_B);
  const int lane = t & 63, q = lane >> 4, n = lane & 15, w = t >> 6;

  // k=0 w3 stage via global_load_lds: waves 0..5 each fill 1 KiB linearly.
  const int wof = __builtin_amdgcn_readfirstlane(w * 1024);
  if (w < 6) {
    const char* gsrc = (const char*)w3f + (size_t)t * 16;
    __builtin_amdgcn_global_load_lds(
        (const __attribute__((address_space(1))) void*)gsrc,
        (__attribute__((address_space(3))) void*)((char*)w3l + wof), 16, 0, 0);
  }

  // acc[ri][mt][i] = logit(SLOT p = mt*16 + q*4 + i) at pixel (x=n, y=w*2+ri).
  f32x4 acc[2][6];
  #pragma unroll
  for (int mt = 0; mt < 6; ++mt)
    #pragma unroll
    for (int i = 0; i < 4; ++i) {
      float bv = 0.f;
      if (mt < 5) {
        int g = mt * 4 + q;                    // 0..19: always valid
        int oc = (g < 18) ? (g >> 1) * 9 + (g & 1) * 4 + i
                          : ((g == 18) ? i * 9 + 8 : 44 + 9 * i);
        bv = b3[oc];
      } else if (q == 0 && i == 0) bv = b3[80];
      acc[0][mt][i] = bv;
      acc[1][mt][i] = bv;
    }

  // stage rgb tile: [row][ch][col] stride 75 (ch offsets 25/50 -> read2-mergeable)
  for (int idx = t; idx < 1728; idx += 512) {
    int c = idx / 576, r2 = idx % 576, ry = r2 / 24, rx = r2 % 24;
    int gy = y0 + ry - 4, gx = x0 + rx - 4;
    float v = 0.f;
    if ((unsigned)gy < (unsigned)HH && (unsigned)gx < (unsigned)WW)
      v = rgb[(size_t)(b * 3 + c) * HWSZ + gy * WW + gx];
    rgbl[ry * 75 + c * 25 + rx] = v;
  }

  // h2T chunk stage from NHWC h2: coalesced f16x8 loads, zero-padded, swizzled.
  auto stageH2 = [&](int cc) {
    for (int idx = t; idx < 1296; idx += 512) {
      int g = idx & 3, pc = idx >> 2;
      int row = pc / 18, col = pc - row * 18;
      int gy = y0 + row - 1, gx = x0 + col - 1;
      f16x8 v = {};
      if ((unsigned)gy < (unsigned)HH && (unsigned)gx < (unsigned)WW)
        v = *(const f16x8*)&h2[(((size_t)b * HH + gy) * WW + gx) * 64 + cc * 32 + g * 8];
      *(f16x8*)&h2T[(row * 18 + col) * 32 + ((g ^ (col & 3)) * 8)] = v;
    }
  };
  stageH2(0);
  __syncthreads();   // also drains the k=0 global_load_lds (vmcnt before barrier)

  // main loop: k = cc*9 + tap in [0,18). w3f offset is simply k*3072 halfs.
  #pragma unroll 1
  for (int cc = 0; cc < 2; ++cc) {
    #pragma unroll 1
    for (int tap = 0; tap < 9; ++tap) {
      const int k = cc * 9 + tap;
      const int cur = k & 1;
      // prefetch next tap's frags straight into the idle LDS buffer (its last
      // readers finished at the barrier ending iteration k-1 -> race-free); the
      // barrier ending THIS iteration drains vmcnt and publishes it for k+1.
      if (k < 17 && w < 6) {
        const char* gsrc = (const char*)(w3f + (k + 1) * 3072) + (size_t)t * 16;
        __builtin_amdgcn_global_load_lds(
            (const __attribute__((address_space(1))) void*)gsrc,
            (__attribute__((address_space(3))) void*)((char*)w3l + (1 - cur) * 6144 + wof),
            16, 0, 0);
      }

      const _Float16* wcur = w3l + cur * 3072;
      const int ty = tap / 3, tx = tap - ty * 3;
      f16x8 bf0, bf1;
      {
        int row0 = w * 2 + ty, col = n + tx;
        int sw = (q ^ (col & 3)) * 8;
        bf0 = *(const f16x8*)&h2T[(row0 * 18 + col) * 32 + sw];
        bf1 = *(const f16x8*)&h2T[((row0 + 1) * 18 + col) * 32 + sw];
      }
      __builtin_amdgcn_s_setprio(1);
      #pragma unroll
      for (int mt = 0; mt < 6; ++mt) {
        f16x8 af = *(const f16x8*)&wcur[(mt * 64 + lane) * 8];
        acc[0][mt] = __builtin_amdgcn_mfma_f32_16x16x32_f16(af, bf0, acc[0][mt], 0, 0, 0);
        acc[1][mt] = __builtin_amdgcn_mfma_f32_16x16x32_f16(af, bf1, acc[1][mt], 0, 0, 0);
      }
      __builtin_amdgcn_s_setprio(0);
      if (k == 8) {            // cc transition: everyone done reading h2T(cc=0)
        __syncthreads();
        stageH2(1);
      }
      __syncthreads();
    }
  }

  // epilogue: per-pixel softmax over 81 taps + bokeh gather (permuted geometry).
  // Lane owns pixel x=n; taps split across q (4 lanes) -> 2-stage shfl reduces.
  #pragma unroll
  for (int ri = 0; ri < 2; ++ri) {
    const int ry0 = w * 2 + ri;                // local y
    float m = -1e30f;
    #pragma unroll
    for (int mt = 0; mt < 5; ++mt)
      #pragma unroll
      for (int i = 0; i < 4; ++i) m = fmaxf(m, acc[ri][mt][i]);
    if (q == 0) m = fmaxf(m, acc[ri][5][0]);
    m = fmaxf(m, __shfl_xor(m, 16));
    m = fmaxf(m, __shfl_xor(m, 32));
    float s = 0.f, a0 = 0.f, a1 = 0.f, a2 = 0.f;
    #pragma unroll
    for (int mt = 0; mt < 5; ++mt) {
      float e[4];
      #pragma unroll
      for (int i = 0; i < 4; ++i) {
        e[i] = __expf(acc[ri][mt][i] - m);
        s += e[i];
      }
      if (mt < 4) {
        // g = mt*4+q in [0,16): horizontal run, step 1 (compile-time)
        int dy = mt * 2 + (q >> 1);
        int base = (ry0 + dy) * 75 + n + (q & 1) * 4;
        #pragma unroll
        for (int i = 0; i < 4; ++i) {
          a0 = fmaf(e[i], rgbl[base + i], a0);
          a1 = fmaf(e[i], rgbl[base + 25 + i], a1);
          a2 = fmaf(e[i], rgbl[base + 50 + i], a2);
        }
      } else {
        // g = 16+q: q<2 horizontal (ty=8, tx0=q*4, step 1); q>=2 vertical
        // (rows (q-2)*4..+3, tx=8, step 75). Per-lane base/step, no divergence.
        int dy = (q < 2) ? 8 : (q - 2) * 4;
        int dx = (q < 2) ? q * 4 : 8;
        int st = (q < 2) ? 1 : 75;
        int base = (ry0 + dy) * 75 + n + dx;
        #pragma unroll
        for (int i = 0; i < 4; ++i) {
          int adr = base + i * st;
          a0 = fmaf(e[i], rgbl[adr], a0);
          a1 = fmaf(e[i], rgbl[adr + 25], a1);
          a2 = fmaf(e[i], rgbl[adr + 50], a2);
        }
      }
    }
    if (q == 0) {                               // slot 80 = tap 80: (ty=8, tx=8)
      float e = __expf(acc[ri][5][0] - m);
      s += e;
      int base = (ry0 + 8) * 75 + n + 8;
      a0 = fmaf(e, rgbl[base], a0);
      a1 = fmaf(e, rgbl[base + 25], a1);
      a2 = fmaf(e, rgbl[base + 50], a2);
    }
    #pragma unroll
    for (int st = 16; st < 64; st <<= 1) {
      s  += __shfl_xor(s, st);
      a0 += __shfl_xor(a0, st);
      a1 += __shfl_xor(a1, st);
      a2 += __shfl_xor(a2, st);
    }
    if (q == 0) {
      float inv = 1.f / s;
      size_t o = (size_t)b * 3 * HWSZ + (size_t)(y0 + ry0) * WW + (x0 + n);
      out[o] = a0 * inv;
      out[o + HWSZ] = a1 * inv;
      out[o + 2 * HWSZ] = a2 * inv;
    }
  }
}

extern "C" void kernel_launch(void* const* d_in, const int* in_sizes, int n_in,
                              void* d_out, int out_size, void* d_ws, size_t ws_size,
                              hipStream_t stream) {
  const float* rgb   = (const float*)d_in[0];
  const float* depth = (const float*)d_in[1];
  const float* w1    = (const float*)d_in[2];
  const float* b1    = (const float*)d_in[3];
  const float* w2    = (const float*)d_in[4];
  const float* b2    = (const float*)d_in[5];
  const float* w3    = (const float*)d_in[6];
  const float* b3    = (const float*)d_in[7];
  char* ws = (char*)d_ws;
  unsigned short* h2 = (unsigned short*)d_ws;
  float* out = (float*)d_out;

  prep<<<376, 256, 0, stream>>>(w1, w2, w3, ws);   // 4096+36864+55296 = 96256 elems

  dim3 grid(WW / 16, HH / 16, NB);  // 24 x 24 x 4
  conv12<<<grid, 256, 0, stream>>>(rgb, depth, b1, b2, ws, h2);
  conv3bokeh<<<grid, 512, 0, stream>>>(h2, rgb, b3, ws, out);
}

// Round 9
// 207.353 us; speedup vs baseline: 1.0597x; 1.0597x over previous
//
#include <hip/hip_runtime.h>
#include <hip/hip_fp16.h>

#define HH 384
#define WW 384
#define HWSZ (HH*WW)   // 147456
#define NB 4

typedef _Float16 f16x8 __attribute__((ext_vector_type(8)));
typedef _Float16 f16x4 __attribute__((ext_vector_type(4)));
typedef _Float16 f16x2 __attribute__((ext_vector_type(2)));
typedef float    f32x4 __attribute__((ext_vector_type(4)));

// ---- ws layout (bytes) ----
// h2 fp16 NHWC [4][384][384][64]: 75,497,472 B @ 0
#define W1A_B 75497472u               // [2 kstep][4 ct][64 lane][8] f16 A-frags, 8192 B
#define W2F_B (W1A_B + 9216u)         // [2][9][4][64][8] f16, 73728 B  (B-frag order)
#define W3F_B (W2F_B + 73728u)        // [2][9][6][64][8] f16, 110592 B (B-frag order, TAP-PERMUTED, co pad 96)
// total 75,691,008 B ~= 72.2 MiB (proven safe)

// w3 output-channel (tap) PERMUTATION: slot p (0..95) -> original tap oc.
// Groups of 4 slots (g = p>>2, i = p&3) map to spatially-regular runs so the
// bokeh gather reads rgbl[base + i*const] (mergeable into ds_read2_b32):
//   g<18 : horizontal run: oc = (g>>1)*9 + (g&1)*4 + i   (ty=g>>1, tx=(g&1)*4+i)
//   g==18: vertical  run: oc = i*9 + 8                   (ty=i,    tx=8)
//   g==19: vertical  run: oc = 44 + 9*i                  (ty=4+i,  tx=8)
//   g==20: single tap 80 (i==0 only)                     (ty=8,    tx=8)
//   else : zero padding
__device__ __forceinline__ int perm_oc(int g, int i, bool& valid) {
  valid = true;
  if (g < 18) return (g >> 1) * 9 + (g & 1) * 4 + i;
  if (g == 18) return i * 9 + 8;
  if (g == 19) return 44 + 9 * i;
  if (g == 20) { valid = (i == 0); return 80; }
  valid = false; return 0;
}

// ---- prep: w1 packed as MFMA A-frags (K = tap*4+ci, 36 -> 2 k-steps of 32),
// w2/w3 packed into MFMA B-fragment order; w3 rows tap-permuted ----
__global__ __launch_bounds__(256) void prep(const float* __restrict__ w1,
    const float* __restrict__ w2, const float* __restrict__ w3, char* __restrict__ ws) {
  int i = blockIdx.x * 256 + threadIdx.x;
  _Float16* w1a = (_Float16*)(ws + W1A_B);
  _Float16* w2f = (_Float16*)(ws + W2F_B);
  _Float16* w3f = (_Float16*)(ws + W3F_B);
  if (i < 4096) {  // w1a linear: kstep*2048 + ct*512 + l*8 + j
    int kstep = i >> 11, r = i & 2047;
    int ct = r >> 9, l = (r >> 3) & 63, j = i & 7;
    int k = kstep * 32 + (l >> 4) * 8 + j;
    int tap = k >> 2, ci = k & 3;
    int co = ct * 16 + (l & 15);
    w1a[i] = (tap < 9) ? (_Float16)w1[co * 36 + ci * 9 + tap] : (_Float16)0.f;
    return;
  }
  int o = i - 4096;
  if (o < 36864) {  // w2f: [cc][tap][cj][lane][j] strides 18432/2048/512/8/1
    int cc = o / 18432, rem = o % 18432;
    int tap = rem >> 11, r2 = rem & 2047;
    int cj = r2 >> 9, l = (r2 >> 3) & 63, j = r2 & 7;
    int co = cj * 16 + (l & 15);
    int ci = cc * 32 + (l >> 4) * 8 + j;
    w2f[o] = (_Float16)w2[co * 576 + ci * 9 + tap];
    return;
  }
  o -= 36864;
  if (o < 55296) {  // w3f: [cc][tap][cj][lane][j] strides 27648/3072/512/8/1
    int cc = o / 27648, rem = o % 27648;
    int tap = rem / 3072, r2 = rem % 3072;
    int cj = r2 >> 9, l = (r2 >> 3) & 63, j = r2 & 7;
    int p = cj * 16 + (l & 15);          // permuted slot
    int ci = cc * 32 + (l >> 4) * 8 + j;
    bool valid;
    int oc = perm_oc(p >> 2, p & 3, valid);
    w3f[o] = valid ? (_Float16)w3[oc * 576 + ci * 9 + tap] : (_Float16)0.f;
  }
}

// ---- stage 1: conv1 (MFMA) + conv2 (MFMA) -> h2 fp16 NHWC ----
// ROUND-6 FORM (best measured; reverted from R7 T14-prefetch +7µs and R8
// w2l-deletion +5µs). Lesson pair: w2l's serial staging is NOT exposed latency —
// 4 blocks/CU wave overlap covers it; both "improvements" only added VGPR
// pressure (R7) or per-cluster VMEM dependencies on the critical path (R8).
// conv1 as implicit GEMM (A = w1 frags in regs, B = x-patches from xwh);
// conv2 3 tap-groups with w2l re-staged between groups.
// Lessons: static acc indexing (R6); no VGPR min-waves cap (R8).
__global__ __launch_bounds__(256) void conv12(
    const float* __restrict__ rgb, const float* __restrict__ depth,
    const float* __restrict__ b1, const float* __restrict__ b2,
    const char* __restrict__ wsro, unsigned short* __restrict__ h2) {
  __shared__ __align__(16) char smem[36864];
  f16x2*    xwh = (f16x2*)smem;                 // 3200 B  [2 cip][20][20] origin (-2,-2)
  _Float16* h1T = (_Float16*)(smem + 3200);     // 20736 B [18*18][32] swizzled
  _Float16* w2l = (_Float16*)(smem + 23936);    // 12288 B [tt][cj][lane*8] (3-tap group)
  _Float16* tr  = (_Float16*)smem;              // epilogue alias: [16][16][72] = 36864 B
  const int t = threadIdx.x;
  const int x0 = blockIdx.x * 16, y0 = blockIdx.y * 16, b = blockIdx.z;
  const f16x8* w1af = (const f16x8*)(wsro + W1A_B);   // [kstep][ct][lane]
  const _Float16* w2f = (const _Float16*)(wsro + W2F_B);
  const int lane = t & 63, q = lane >> 4, n = lane & 15, w = t >> 6;

  // stage input tile as ci-pairs: pair0=(r,g), pair1=(b,depth)
  for (int idx = t; idx < 800; idx += 256) {
    int p = idx / 400, r2 = idx % 400, iy = r2 / 20, ix = r2 % 20;
    int gy = y0 + iy - 2, gx = x0 + ix - 2;
    f16x2 v = {(_Float16)0.f, (_Float16)0.f};
    if ((unsigned)gy < (unsigned)HH && (unsigned)gx < (unsigned)WW) {
      size_t off = (size_t)gy * WW + gx;
      int c0 = p * 2;
      float f0 = rgb[(size_t)(b * 3 + c0) * HWSZ + off];             // c0 = 0 or 2
      float f1 = (c0 + 1 < 3) ? rgb[(size_t)(b * 3 + c0 + 1) * HWSZ + off]
                              : depth[(size_t)b * HWSZ + off];
      v[0] = (_Float16)f0; v[1] = (_Float16)f1;
    }
    xwh[idx] = v;
  }

  f32x4 acc[4][4];
  #pragma unroll
  for (int cj = 0; cj < 4; ++cj) {
    float bv = b2[cj * 16 + n];
    #pragma unroll
    for (int ri = 0; ri < 4; ++ri) acc[ri][cj] = (f32x4){bv, bv, bv, bv};
  }
  __syncthreads();

  for (int cc = 0; cc < 2; ++cc) {
    // stage w2 tap-group 0 (issues first; latency hides under conv1)
    {
      const float4* src = (const float4*)(w2f + cc * 18432);
      float4* dst = (float4*)w2l;
      for (int idx = t; idx < 768; idx += 256) dst[idx] = src[idx];
    }
    // per-cc w1 A-frags + bias (STATIC register indexing; cc only in the address)
    f16x8 wa[2][2];
    #pragma unroll
    for (int ks = 0; ks < 2; ++ks)
      #pragma unroll
      for (int c2 = 0; c2 < 2; ++c2)
        wa[ks][c2] = w1af[(ks * 4 + cc * 2 + c2) * 64 + lane];
    float4 bia[2];
    #pragma unroll
    for (int c2 = 0; c2 < 2; ++c2)
      bia[c2] = *(const float4*)&b1[(cc * 2 + c2) * 16 + q * 4];

    // conv1 MFMA: 21 m-tiles of 16 px over the 18x18 halo, waves strided by 4.
    #pragma unroll 1
    for (int tile = w; tile < 21; tile += 4) {
      int px = tile * 16 + n;
      int pxc = px < 323 ? px : 323;           // clamp keeps reads in-bounds/real
      int row = pxc / 18, col = pxc - row * 18;
      bool okp = ((unsigned)(y0 + row - 1) < (unsigned)HH) &&
                 ((unsigned)(x0 + col - 1) < (unsigned)WW);
      // B-frag k-step0: taps q*2, q*2+1; halfs = {ci0..3}@tap0, {ci0..3}@tap1
      int t0 = q * 2, t1 = t0 + 1;
      int ky0 = t0 / 3, kx0 = t0 - ky0 * 3;
      int ky1 = t1 / 3, kx1 = t1 - ky1 * 3;
      f16x2 p00 = xwh[(row + ky0) * 20 + col + kx0];
      f16x2 p01 = xwh[400 + (row + ky0) * 20 + col + kx0];
      f16x2 p10 = xwh[(row + ky1) * 20 + col + kx1];
      f16x2 p11 = xwh[400 + (row + ky1) * 20 + col + kx1];
      f16x8 bf0 = {p00[0], p00[1], p01[0], p01[1], p10[0], p10[1], p11[0], p11[1]};
      // B-frag k-step1: only k=32..35 valid (tap 8, q==0); rest MUST be 0 (A is
      // zero there, and 0*NaN would poison the dot).
      f16x8 bf1 = {};
      if (q == 0) {
        f16x2 p80 = xwh[(row + 2) * 20 + col + 2];
        f16x2 p81 = xwh[400 + (row + 2) * 20 + col + 2];
        bf1[0] = p80[0]; bf1[1] = p80[1]; bf1[2] = p81[0]; bf1[3] = p81[1];
      }
      #pragma unroll
      for (int c2 = 0; c2 < 2; ++c2) {
        f32x4 a = (f32x4){bia[c2].x, bia[c2].y, bia[c2].z, bia[c2].w};
        a = __builtin_amdgcn_mfma_f32_16x16x32_f16(wa[0][c2], bf0, a, 0, 0, 0);
        a = __builtin_amdgcn_mfma_f32_16x16x32_f16(wa[1][c2], bf1, a, 0, 0, 0);
        if (px < 324) {
          f16x4 hv;
          #pragma unroll
          for (int i = 0; i < 4; ++i)
            hv[i] = okp ? (_Float16)fmaxf(a[i], 0.f) : (_Float16)0.f;
          int g = c2 * 2 + (q >> 1);           // co_in_cc = c2*16+q*4+i; g = /8
          *(f16x4*)&h1T[pxc * 32 + ((g ^ (col & 3)) * 8 + (q & 1) * 4)] = hv;
        }
      }
    }
    __syncthreads();

    // conv2 MFMA in 3 tap-groups (ty = tg, tx = tt); w2l re-staged between groups.
    #pragma unroll 1
    for (int tg = 0; tg < 3; ++tg) {
      #pragma unroll
      for (int tt = 0; tt < 3; ++tt) {
        f16x8 af[4];
        #pragma unroll
        for (int ri = 0; ri < 4; ++ri) {
          int row = w * 4 + ri + tg;           // 0..17
          int col = n + tt;                    // A-frag m = lane&15 = x
          af[ri] = *(const f16x8*)&h1T[(row * 18 + col) * 32 + ((q ^ (col & 3)) * 8)];
        }
        #pragma unroll
        for (int cj = 0; cj < 4; ++cj) {
          f16x8 bf = *(const f16x8*)&w2l[(tt * 4 + cj) * 512 + lane * 8];
          #pragma unroll
          for (int ri = 0; ri < 4; ++ri)
            acc[ri][cj] = __builtin_amdgcn_mfma_f32_16x16x32_f16(af[ri], bf, acc[ri][cj], 0, 0, 0);
        }
      }
      __syncthreads();                          // all waves done reading w2l group tg
      if (tg < 2) {
        const float4* src = (const float4*)(w2f + cc * 18432 + (tg + 1) * 6144);
        float4* dst = (float4*)w2l;
        for (int idx = t; idx < 768; idx += 256) dst[idx] = src[idx];
        __syncthreads();
      }
    }
  }

  // epilogue: ReLU + fp16, transpose via LDS (tr aliases all of smem), NHWC store.
  // D layout: x = q*4+i, co = cj*16+n, y = w*4+ri.
  #pragma unroll
  for (int ri = 0; ri < 4; ++ri) {
    int py = w * 4 + ri;
    #pragma unroll
    for (int cj = 0; cj < 4; ++cj)
      #pragma unroll
      for (int i = 0; i < 4; ++i)
        tr[(py * 16 + q * 4 + i) * 72 + cj * 16 + n] = (_Float16)fmaxf(acc[ri][cj][i], 0.f);
  }
  __syncthreads();
  #pragma unroll
  for (int k = 0; k < 8; ++k) {
    int idx = t + k * 256;                     // [0,2048): y | x | c8
    int y = idx >> 7, x = (idx >> 3) & 15, c8 = (idx & 7) * 8;
    f16x8 v = *(const f16x8*)&tr[(y * 16 + x) * 72 + c8];
    *(f16x8*)&h2[(((size_t)b * HH + y0 + y) * WW + x0 + x) * 64 + c8] = v;
  }
}

// ---- stage 2: conv3 (MFMA) + softmax + bokeh ---- (ROUND-6 FORM — frozen)
// At its structural LDS floor (~89% LDS-pipe busy): tap-split restructures are
// a wash, wider tiles hit the R4 register cliff (VGPR>64 halves waves, R5),
// fp8 operands break absmax. VGPR 44, 8 waves, permuted gather, gload_lds
// ping-pong.
__global__ __launch_bounds__(512) void conv3bokeh(
    const unsigned short* __restrict__ h2, const float* __restrict__ rgb,
    const float* __restrict__ b3, const char* __restrict__ wsro,
    float* __restrict__ out) {
  __shared__ __align__(16) char smem[40224];
  _Float16* h2T  = (_Float16*)smem;             // 20736 B [18*18][32] swizzled
  _Float16* w3l  = (_Float16*)(smem + 20736);   // 12288 B = 2 x [mt 6][lane 64][8] ping-pong
  float*    rgbl = (float*)(smem + 33024);      // 7200 B [24 row][3 ch][25 col], origin (-4,-4)
  const int t = threadIdx.x;
  const int x0 = blockIdx.x * 16, y0 = blockIdx.y * 16, b = blockIdx.z;
  const _Float16* w3f = (const _Float16*)(wsro + W3F_B);
  const int lane = t & 63, q = lane >> 4, n = lane & 15, w = t >> 6;

  // k=0 w3 stage via global_load_lds: waves 0..5 each fill 1 KiB linearly.
  const int wof = __builtin_amdgcn_readfirstlane(w * 1024);
  if (w < 6) {
    const char* gsrc = (const char*)w3f + (size_t)t * 16;
    __builtin_amdgcn_global_load_lds(
        (const __attribute__((address_space(1))) void*)gsrc,
        (__attribute__((address_space(3))) void*)((char*)w3l + wof), 16, 0, 0);
  }

  // acc[ri][mt][i] = logit(SLOT p = mt*16 + q*4 + i) at pixel (x=n, y=w*2+ri).
  f32x4 acc[2][6];
  #pragma unroll
  for (int mt = 0; mt < 6; ++mt)
    #pragma unroll
    for (int i = 0; i < 4; ++i) {
      float bv = 0.f;
      if (mt < 5) {
        int g = mt * 4 + q;                    // 0..19: always valid
        int oc = (g < 18) ? (g >> 1) * 9 + (g & 1) * 4 + i
                          : ((g == 18) ? i * 9 + 8 : 44 + 9 * i);
        bv = b3[oc];
      } else if (q == 0 && i == 0) bv = b3[80];
      acc[0][mt][i] = bv;
      acc[1][mt][i] = bv;
    }

  // stage rgb tile: [row][ch][col] stride 75 (ch offsets 25/50 -> read2-mergeable)
  for (int idx = t; idx < 1728; idx += 512) {
    int c = idx / 576, r2 = idx % 576, ry = r2 / 24, rx = r2 % 24;
    int gy = y0 + ry - 4, gx = x0 + rx - 4;
    float v = 0.f;
    if ((unsigned)gy < (unsigned)HH && (unsigned)gx < (unsigned)WW)
      v = rgb[(size_t)(b * 3 + c) * HWSZ + gy * WW + gx];
    rgbl[ry * 75 + c * 25 + rx] = v;
  }

  // h2T chunk stage from NHWC h2: coalesced f16x8 loads, zero-padded, swizzled.
  auto stageH2 = [&](int cc) {
    for (int idx = t; idx < 1296; idx += 512) {
      int g = idx & 3, pc = idx >> 2;
      int row = pc / 18, col = pc - row * 18;
      int gy = y0 + row - 1, gx = x0 + col - 1;
      f16x8 v = {};
      if ((unsigned)gy < (unsigned)HH && (unsigned)gx < (unsigned)WW)
        v = *(const f16x8*)&h2[(((size_t)b * HH + gy) * WW + gx) * 64 + cc * 32 + g * 8];
      *(f16x8*)&h2T[(row * 18 + col) * 32 + ((g ^ (col & 3)) * 8)] = v;
    }
  };
  stageH2(0);
  __syncthreads();   // also drains the k=0 global_load_lds (vmcnt before barrier)

  // main loop: k = cc*9 + tap in [0,18). w3f offset is simply k*3072 halfs.
  #pragma unroll 1
  for (int cc = 0; cc < 2; ++cc) {
    #pragma unroll 1
    for (int tap = 0; tap < 9; ++tap) {
      const int k = cc * 9 + tap;
      const int cur = k & 1;
      // prefetch next tap's frags straight into the idle LDS buffer (its last
      // readers finished at the barrier ending iteration k-1 -> race-free); the
      // barrier ending THIS iteration drains vmcnt and publishes it for k+1.
      if (k < 17 && w < 6) {
        const char* gsrc = (const char*)(w3f + (k + 1) * 3072) + (size_t)t * 16;
        __builtin_amdgcn_global_load_lds(
            (const __attribute__((address_space(1))) void*)gsrc,
            (__attribute__((address_space(3))) void*)((char*)w3l + (1 - cur) * 6144 + wof),
            16, 0, 0);
      }

      const _Float16* wcur = w3l + cur * 3072;
      const int ty = tap / 3, tx = tap - ty * 3;
      f16x8 bf0, bf1;
      {
        int row0 = w * 2 + ty, col = n + tx;
        int sw = (q ^ (col & 3)) * 8;
        bf0 = *(const f16x8*)&h2T[(row0 * 18 + col) * 32 + sw];
        bf1 = *(const f16x8*)&h2T[((row0 + 1) * 18 + col) * 32 + sw];
      }
      __builtin_amdgcn_s_setprio(1);
      #pragma unroll
      for (int mt = 0; mt < 6; ++mt) {
        f16x8 af = *(const f16x8*)&wcur[(mt * 64 + lane) * 8];
        acc[0][mt] = __builtin_amdgcn_mfma_f32_16x16x32_f16(af, bf0, acc[0][mt], 0, 0, 0);
        acc[1][mt] = __builtin_amdgcn_mfma_f32_16x16x32_f16(af, bf1, acc[1][mt], 0, 0, 0);
      }
      __builtin_amdgcn_s_setprio(0);
      if (k == 8) {            // cc transition: everyone done reading h2T(cc=0)
        __syncthreads();
        stageH2(1);
      }
      __syncthreads();
    }
  }

  // epilogue: per-pixel softmax over 81 taps + bokeh gather (permuted geometry).
  // Lane owns pixel x=n; taps split across q (4 lanes) -> 2-stage shfl reduces.
  #pragma unroll
  for (int ri = 0; ri < 2; ++ri) {
    const int ry0 = w * 2 + ri;                // local y
    float m = -1e30f;
    #pragma unroll
    for (int mt = 0; mt < 5; ++mt)
      #pragma unroll
      for (int i = 0; i < 4; ++i) m = fmaxf(m, acc[ri][mt][i]);
    if (q == 0) m = fmaxf(m, acc[ri][5][0]);
    m = fmaxf(m, __shfl_xor(m, 16));
    m = fmaxf(m, __shfl_xor(m, 32));
    float s = 0.f, a0 = 0.f, a1 = 0.f, a2 = 0.f;
    #pragma unroll
    for (int mt = 0; mt < 5; ++mt) {
      float e[4];
      #pragma unroll
      for (int i = 0; i < 4; ++i) {
        e[i] = __expf(acc[ri][mt][i] - m);
        s += e[i];
      }
      if (mt < 4) {
        // g = mt*4+q in [0,16): horizontal run, step 1 (compile-time)
        int dy = mt * 2 + (q >> 1);
        int base = (ry0 + dy) * 75 + n + (q & 1) * 4;
        #pragma unroll
        for (int i = 0; i < 4; ++i) {
          a0 = fmaf(e[i], rgbl[base + i], a0);
          a1 = fmaf(e[i], rgbl[base + 25 + i], a1);
          a2 = fmaf(e[i], rgbl[base + 50 + i], a2);
        }
      } else {
        // g = 16+q: q<2 horizontal (ty=8, tx0=q*4, step 1); q>=2 vertical
        // (rows (q-2)*4..+3, tx=8, step 75). Per-lane base/step, no divergence.
        int dy = (q < 2) ? 8 : (q - 2) * 4;
        int dx = (q < 2) ? q * 4 : 8;
        int st = (q < 2) ? 1 : 75;
        int base = (ry0 + dy) * 75 + n + dx;
        #pragma unroll
        for (int i = 0; i < 4; ++i) {
          int adr = base + i * st;
          a0 = fmaf(e[i], rgbl[adr], a0);
          a1 = fmaf(e[i], rgbl[adr + 25], a1);
          a2 = fmaf(e[i], rgbl[adr + 50], a2);
        }
      }
    }
    if (q == 0) {                               // slot 80 = tap 80: (ty=8, tx=8)
      float e = __expf(acc[ri][5][0] - m);
      s += e;
      int base = (ry0 + 8) * 75 + n + 8;
      a0 = fmaf(e, rgbl[base], a0);
      a1 = fmaf(e, rgbl[base + 25], a1);
      a2 = fmaf(e, rgbl[base + 50], a2);
    }
    #pragma unroll
    for (int st = 16; st < 64; st <<= 1) {
      s  += __shfl_xor(s, st);
      a0 += __shfl_xor(a0, st);
      a1 += __shfl_xor(a1, st);
      a2 += __shfl_xor(a2, st);
    }
    if (q == 0) {
      float inv = 1.f / s;
      size_t o = (size_t)b * 3 * HWSZ + (size_t)(y0 + ry0) * WW + (x0 + n);
      out[o] = a0 * inv;
      out[o + HWSZ] = a1 * inv;
      out[o + 2 * HWSZ] = a2 * inv;
    }
  }
}

extern "C" void kernel_launch(void* const* d_in, const int* in_sizes, int n_in,
                              void* d_out, int out_size, void* d_ws, size_t ws_size,
                              hipStream_t stream) {
  const float* rgb   = (const float*)d_in[0];
  const float* depth = (const float*)d_in[1];
  const float* w1    = (const float*)d_in[2];
  const float* b1    = (const float*)d_in[3];
  const float* w2    = (const float*)d_in[4];
  const float* b2    = (const float*)d_in[5];
  const float* w3    = (const float*)d_in[6];
  const float* b3    = (const float*)d_in[7];
  char* ws = (char*)d_ws;
  unsigned short* h2 = (unsigned short*)d_ws;
  float* out = (float*)d_out;

  prep<<<376, 256, 0, stream>>>(w1, w2, w3, ws);   // 4096+36864+55296 = 96256 elems

  dim3 grid(WW / 16, HH / 16, NB);  // 24 x 24 x 4
  conv12<<<grid, 256, 0, stream>>>(rgb, depth, b1, b2, ws, h2);
  conv3bokeh<<<grid, 512, 0, stream>>>(h2, rgb, b3, ws, out);
}